// Round 8
// baseline (248.442 us; speedup 1.0000x reference)
//
#include <hip/hip_runtime.h>
#include <math.h>

#define B_ 16
#define LC_ 512
#define LP_ 4096
#define H_ 128
#define HH_ (H_*H_)

typedef unsigned long long u64t;
typedef unsigned short u16t;
typedef __attribute__((ext_vector_type(8))) short bf16x8;
typedef __attribute__((ext_vector_type(4))) float f32x4;

__device__ __forceinline__ u16t f2bf(float f) {
    union { float f; unsigned u; } v; v.f = f;
    unsigned r = (v.u + 0x7FFFu + ((v.u >> 16) & 1u)) >> 16;
    return (u16t)r;
}
__device__ __forceinline__ float bf2f(u16t s) {
    union { unsigned u; float f; } v; v.u = ((unsigned)s) << 16; return v.f;
}
__device__ __forceinline__ float bflo(unsigned u) {
    union { unsigned u; float f; } v; v.u = u << 16; return v.f;
}
__device__ __forceinline__ float bfhi(unsigned u) {
    union { unsigned u; float f; } v; v.u = u & 0xffff0000u; return v.f;
}
__device__ __forceinline__ float ftanh(float x) {
    x = fminf(15.f, fmaxf(-15.f, x));
    float t = __expf(2.f * x);
    return (t - 1.f) / (t + 1.f);
}
__device__ __forceinline__ bf16x8 ldfragS(const short* base, int r, int k, int stride) {
    const u64t* p = (const u64t*)(base + (size_t)r * stride + k);
    union { bf16x8 v; u64t q[2]; } u;
    u.q[0] = p[0]; u.q[1] = p[1];
    return u.v;
}
__device__ __forceinline__ bf16x8 ldfragG(const u16t* p) {
    union { bf16x8 v; uint4 q; } u;
    u.q = *(const uint4*)p;
    return u.v;
}

// ---- one-shot: fp32 W[k][n] -> transposed bf16 hi/lo [n][k] ----
__device__ __forceinline__ void wprep_body(const float* __restrict__ src,
                                           u16t* __restrict__ h, u16t* __restrict__ l,
                                           int t) {
    const int n = t >> 1, k0 = (t & 1) * 64;
#pragma unroll 4
    for (int k = 0; k < 64; ++k) {
        float v = src[(size_t)(k0 + k) * H_ + n];
        u16t hh = f2bf(v);
        h[(size_t)n * H_ + k0 + k] = hh;
        l[(size_t)n * H_ + k0 + k] = f2bf(v - bf2f(hh));
    }
}
// grid (3 layers, 3 groups): group 0=Wp, 1=Wc, 2=Wbl. dst index = grp*3+lay.
__global__ __launch_bounds__(256) void wprep3_k(const float* __restrict__ s0,
                                                const float* __restrict__ s1,
                                                const float* __restrict__ s2,
                                                u16t* __restrict__ hi,
                                                u16t* __restrict__ lo) {
    const int lay = blockIdx.x, grp = blockIdx.y;
    const float* src = (grp == 0 ? s0 : grp == 1 ? s1 : s2) + (size_t)lay * HH_;
    const size_t o = ((size_t)grp * 3 + lay) * HH_;
    wprep_body(src, hi + o, lo + o, threadIdx.x);
}
// grid (B, 2): which 0=M(lay2), 1=N(lay2). dst index = which*B+b.
__global__ __launch_bounds__(256) void wprepMN_k(const float* __restrict__ M,
                                                 const float* __restrict__ N,
                                                 u16t* __restrict__ hi,
                                                 u16t* __restrict__ lo) {
    const int b = blockIdx.x, which = blockIdx.y;
    const float* src = (which ? N : M) + ((size_t)2 * B_ + b) * HH_;
    const size_t o = ((size_t)which * B_ + b) * HH_;
    wprep_body(src, hi + o, lo + o, threadIdx.x);
}

// bf16 src [64 k][128 h] (+ optional per-k mask) -> transposed [128 h][68] bf16 tile.
__device__ __forceinline__ void stage64_bf(const u16t* __restrict__ src,
                                           const int* __restrict__ maskrow,
                                           short* __restrict__ dst, int t) {
    const int m = t & 31, kq = t >> 5;
#pragma unroll
    for (int p = 0; p < 2; ++p) {
        const int kc = p * 32 + kq * 4;
        u64t q[4];
#pragma unroll
        for (int r = 0; r < 4; ++r) {
            u64t v = *(const u64t*)(src + (size_t)(kc + r) * H_ + m * 4);
            if (maskrow && !maskrow[kc + r]) v = 0;
            q[r] = v;
        }
#pragma unroll
        for (int i = 0; i < 4; ++i) {
            u64t val = ((q[0] >> (16 * i)) & 0xffffull)
                     | (((q[1] >> (16 * i)) & 0xffffull) << 16)
                     | (((q[2] >> (16 * i)) & 0xffffull) << 32)
                     | (((q[3] >> (16 * i)) & 0xffffull) << 48);
            *(u64t*)(dst + (size_t)(4 * m + i) * 68 + kc) = val;
        }
    }
}

// ---- MFMA GEMM, W-fragments direct from global hi/lo [n][k] bf16 ----
// grid: (rows/64, 2 n-halves, nWsel). XPERW: X strided by wsel (else shared).
template<bool TANH, bool BF16OUT, bool XPERW, bool BIASPERW>
__global__ __launch_bounds__(256) void hgemm2_k(const u16t* __restrict__ Xall,
                                                const u16t* __restrict__ WhiAll,
                                                const u16t* __restrict__ WloAll,
                                                const float* __restrict__ biasAll,
                                                const int* __restrict__ mask,
                                                void* __restrict__ Yout,
                                                int rows) {
    __shared__ __align__(16) short Xs[64 * 136];
    const int t = threadIdx.x;
    const int wsel = blockIdx.z, nh = blockIdx.y;
    const long yrow0 = (long)wsel * rows + (long)blockIdx.x * 64;
    const u16t* X = XPERW ? (Xall + (size_t)yrow0 * H_)
                          : (Xall + (size_t)blockIdx.x * 64 * H_);
    const u16t* Whi = WhiAll + (size_t)wsel * HH_;
    const u16t* Wlo = WloAll + (size_t)wsel * HH_;

    {
        const uint4* src = (const uint4*)X;
#pragma unroll
        for (int j = 0; j < 4; ++j) {
            int lin = j * 256 + t;
            *(uint4*)(Xs + (lin >> 4) * 136 + (lin & 15) * 8) = src[lin];
        }
    }
    __syncthreads();

    const int l = t & 63, w = t >> 6;
    const int lm = l & 15, lk = (l >> 4) * 8, lr = (l >> 4) * 4;
    const int colg = nh * 64 + w * 16 + lm;   // global output col
    const size_t wrow = (size_t)colg * H_;
    f32x4 acc[4] = {};
#pragma unroll
    for (int ks = 0; ks < 128; ks += 32) {
        bf16x8 bh = ldfragG(Whi + wrow + ks + lk);
        bf16x8 bl = ldfragG(Wlo + wrow + ks + lk);
#pragma unroll
        for (int it = 0; it < 4; ++it) {
            bf16x8 af = ldfragS(Xs, it * 16 + lm, ks + lk, 136);
            acc[it] = __builtin_amdgcn_mfma_f32_16x16x32_bf16(af, bh, acc[it], 0, 0, 0);
            acc[it] = __builtin_amdgcn_mfma_f32_16x16x32_bf16(af, bl, acc[it], 0, 0, 0);
        }
    }

    const float bv = biasAll ? biasAll[(BIASPERW ? wsel * H_ : 0) + colg] : 0.f;
#pragma unroll
    for (int it = 0; it < 4; ++it) {
#pragma unroll
        for (int r = 0; r < 4; ++r) {
            long row = yrow0 + it * 16 + lr + r;
            float v = acc[it][r] + bv;
            if (TANH) v = ftanh(v);
            if (mask) v *= (float)mask[row];
            if (BF16OUT) ((u16t*)Yout)[(size_t)row * H_ + colg] = f2bf(v);
            else ((float*)Yout)[(size_t)row * H_ + colg] = v;
        }
    }
}

// part[lay][slice][b] = sum over slice's k of (mask*Xl[lay,b,k,:])^T outer Yr[lay,b,k,:]
template<bool SAME>
__global__ __launch_bounds__(256) void syrk_mfma_k(const u16t* __restrict__ Xl,
                                                   const u16t* __restrict__ Yr,
                                                   const int* __restrict__ mask,
                                                   float* __restrict__ part,
                                                   int Kb, int rowsPerSlice, int slices) {
    extern __shared__ short smem[];
    short* Xt = smem;
    short* Yt = SAME ? smem : (smem + 128 * 68);
    const int t = threadIdx.x;
    const int b = blockIdx.y, slice = blockIdx.x, lay = blockIdx.z;
    const int l = t & 63, w = t >> 6;
    const int qi = (w >> 1) * 64, qj = (w & 1) * 64;
    const int lm = l & 15, lk = (l >> 4) * 8, lr = (l >> 4) * 4;

    f32x4 acc[4][4] = {};
    const int chunks = rowsPerSlice >> 6;
    const size_t doff = ((size_t)lay * B_ + b) * Kb;
    const size_t moff = (size_t)b * Kb;

    for (int c = 0; c < chunks; ++c) {
        const int kbase = slice * rowsPerSlice + c * 64;
        stage64_bf(Xl + (doff + kbase) * H_, mask + moff + kbase, Xt, t);
        if (!SAME) stage64_bf(Yr + (doff + kbase) * H_, nullptr, Yt, t);
        __syncthreads();
#pragma unroll
        for (int ks = 0; ks < 64; ks += 32) {
            bf16x8 af[4], bfr[4];
#pragma unroll
            for (int it = 0; it < 4; ++it) af[it] = ldfragS(Xt, qi + it * 16 + lm, ks + lk, 68);
#pragma unroll
            for (int jt = 0; jt < 4; ++jt) bfr[jt] = ldfragS(Yt, qj + jt * 16 + lm, ks + lk, 68);
#pragma unroll
            for (int it = 0; it < 4; ++it)
#pragma unroll
                for (int jt = 0; jt < 4; ++jt)
                    acc[it][jt] = __builtin_amdgcn_mfma_f32_16x16x32_bf16(
                        af[it], bfr[jt], acc[it][jt], 0, 0, 0);
        }
        __syncthreads();
    }

    float* pb = part + (((size_t)lay * slices + slice) * B_ + b) * HH_;
#pragma unroll
    for (int it = 0; it < 4; ++it)
#pragma unroll
        for (int jt = 0; jt < 4; ++jt)
#pragma unroll
            for (int r = 0; r < 4; ++r)
                pb[(size_t)(qi + it * 16 + lr + r) * H_ + qj + jt * 16 + lm] = acc[it][jt][r];
}

__global__ __launch_bounds__(256) void reduce_k(const float4* __restrict__ part,
                                                float4* __restrict__ out, int slices) {
    const int lay = blockIdx.y;
    const size_t idx = (size_t)blockIdx.x * 256 + threadIdx.x;
    const size_t quarter = (size_t)B_ * HH_ / 4;
    const float4* p = part + (size_t)lay * slices * quarter;
    float4 a = p[idx];
    for (int s = 1; s < slices; ++s) {
        float4 v = p[(size_t)s * quarter + idx];
        a.x += v.x; a.y += v.y; a.z += v.z; a.w += v.w;
    }
    (out + (size_t)lay * quarter)[idx] = a;
}

__global__ void tobf16_k(const float4* __restrict__ in, uint4* __restrict__ out) {
    int idx = blockIdx.x * 256 + threadIdx.x;
    float4 a = in[2 * idx], b = in[2 * idx + 1];
    uint4 o;
    o.x = (unsigned)f2bf(a.x) | ((unsigned)f2bf(a.y) << 16);
    o.y = (unsigned)f2bf(a.z) | ((unsigned)f2bf(a.w) << 16);
    o.z = (unsigned)f2bf(b.x) | ((unsigned)f2bf(b.y) << 16);
    o.w = (unsigned)f2bf(b.z) | ((unsigned)f2bf(b.w) << 16);
    out[idx] = o;
}

// ---- vc[lay,b] = M[lay,b] @ Wac[lay] ; vp[lay,b] = N[lay,b] @ Wap[lay] ----
__global__ void mv_k(const float* __restrict__ M, const float* __restrict__ N,
                     const float* __restrict__ WacAll, const float* __restrict__ WapAll,
                     float* __restrict__ vcAll, float* __restrict__ vpAll) {
    const int b = blockIdx.x, lay = blockIdx.y, t = threadIdx.x;
    const size_t mo = ((size_t)lay * B_ + b) * HH_;
    const float* mat = (t < 128) ? (M + mo + (size_t)t * H_) : (N + mo + (size_t)(t - 128) * H_);
    const float* w = (t < 128) ? (WacAll + lay * H_) : (WapAll + lay * H_);
    float acc = 0.f;
#pragma unroll 8
    for (int h = 0; h < H_; ++h) acc = fmaf(mat[h], w[h], acc);
    if (t < 128) vcAll[((size_t)lay * B_ + b) * H_ + t] = acc;
    else         vpAll[((size_t)lay * B_ + b) * H_ + (t - 128)] = acc;
}

// ---- logits[lay,b,r] = mask[b,r] * (feat[lay,b,r,:] . v[lay,b]) + bias[lay] ----
template<int N>
__global__ __launch_bounds__(256) void logits2_k(const u16t* __restrict__ featAll,
                                                 const int* __restrict__ maskAll,
                                                 const float* __restrict__ vAll,
                                                 const float* __restrict__ bvAll,
                                                 float* __restrict__ out) {
    __shared__ float v[H_];
    const int b = blockIdx.y, lay = blockIdx.z, t = threadIdx.x;
    if (t < 128) v[t] = vAll[((size_t)lay * B_ + b) * H_ + t];
    __syncthreads();
    const int r = blockIdx.x * 256 + t;
    const uint2* f2 = (const uint2*)(featAll + (((size_t)lay * B_ + b) * (size_t)N + r) * H_);
    const float4* v4 = (const float4*)v;
    float acc = 0.f;
#pragma unroll
    for (int h4 = 0; h4 < 32; ++h4) {
        uint2 u = f2[h4];
        float4 c = v4[h4];
        acc = fmaf(bflo(u.x), c.x, acc); acc = fmaf(bfhi(u.x), c.y, acc);
        acc = fmaf(bflo(u.y), c.z, acc); acc = fmaf(bfhi(u.y), c.w, acc);
    }
    out[((size_t)lay * B_ + b) * N + r] = (float)maskAll[(size_t)b * N + r] * acc + bvAll[lay];
}

// ---- masked softmax, faithful: max over ALL, exp*mask, denom + 1e-6 ----
template<int N>
__global__ __launch_bounds__(256) void softmax_k(const float* __restrict__ logits,
                                                 const int* __restrict__ mask,
                                                 float* __restrict__ w) {
    const int b = blockIdx.x, lay = blockIdx.y, t = threadIdx.x;
    const float* l = logits + ((size_t)lay * B_ + b) * N;
    const int* mk = mask + (size_t)b * N;
    float* ww = w + ((size_t)lay * B_ + b) * N;
    __shared__ float Es[N];
    __shared__ float red[4];

    float mx = -1e30f;
    for (int q = t; q < N; q += 256) { float x = l[q]; Es[q] = x; mx = fmaxf(mx, x); }
#pragma unroll
    for (int o = 32; o > 0; o >>= 1) mx = fmaxf(mx, __shfl_down(mx, o, 64));
    if ((t & 63) == 0) red[t >> 6] = mx;
    __syncthreads();
    float m = fmaxf(fmaxf(red[0], red[1]), fmaxf(red[2], red[3]));
    __syncthreads();

    float s = 0.f;
    for (int q = t; q < N; q += 256) {
        float e = __expf(Es[q] - m) * (float)mk[q];
        Es[q] = e;
        s += e;
    }
#pragma unroll
    for (int o = 32; o > 0; o >>= 1) s += __shfl_down(s, o, 64);
    if ((t & 63) == 0) red[t >> 6] = s;
    __syncthreads();
    float denom = red[0] + red[1] + red[2] + red[3] + 1e-6f;
    for (int q = t; q < N; q += 256) ww[q] = Es[q] / denom;
}

// ---- pooled[lay,b,h] += sum_{q in chunk} proj_bf16[lay,b,q,h] * w[lay,b,q] ----
__global__ __launch_bounds__(256) void pool_k(const u16t* __restrict__ proj,
                                              const float* __restrict__ w,
                                              float* __restrict__ out, int n, int chunk) {
    const int b = blockIdx.x, lay = blockIdx.z, t = threadIdx.x;
    const int th = t & 63, tq = t >> 6;
    const int q0 = blockIdx.y * chunk;
    const u16t* pb = proj + (((size_t)lay * B_ + b) * n + q0) * H_;
    const float* wb = w + ((size_t)lay * B_ + b) * n + q0;
    float a0 = 0.f, a1 = 0.f;
    for (int q = tq; q < chunk; q += 4) {
        float wq = wb[q];
        unsigned u = *(const unsigned*)(pb + (size_t)q * H_ + th * 2);
        a0 = fmaf(bflo(u), wq, a0);
        a1 = fmaf(bfhi(u), wq, a1);
    }
    float* ob = out + ((size_t)lay * B_ + b) * H_;
    atomicAdd(&ob[th * 2], a0);
    atomicAdd(&ob[th * 2 + 1], a1);
}

// ---- final[b,h] += sum_{j in chunk} pooled[j>>7, b, j&127] * Wcomb[j,h] (+bias) ----
__global__ void final2_k(const float* __restrict__ pooled, const float* __restrict__ Wcomb,
                         const float* __restrict__ bcomb, float* __restrict__ out) {
    const int b = blockIdx.x, h = threadIdx.x, j0 = blockIdx.y * 64;
    float acc = (blockIdx.y == 0) ? bcomb[h] : 0.f;
#pragma unroll 4
    for (int j = 0; j < 64; ++j) {
        int jj = j0 + j;
        int lay = jj >> 7, hh = jj & 127;
        acc = fmaf(pooled[((size_t)lay * B_ + b) * H_ + hh], Wcomb[(size_t)jj * H_ + h], acc);
    }
    atomicAdd(&out[b * H_ + h], acc);
}

extern "C" void kernel_launch(void* const* d_in, const int* in_sizes, int n_in,
                              void* d_out, int out_size, void* d_ws, size_t ws_size,
                              hipStream_t stream) {
    const float* comp_feat = (const float*)d_in[0];
    const int*   comp_mask = (const int*)d_in[1];
    const float* prot_feat = (const float*)d_in[2];
    const int*   prot_mask = (const int*)d_in[3];
    const float* Wc      = (const float*)d_in[4];
    const float* bc      = (const float*)d_in[5];
    const float* Wp      = (const float*)d_in[6];
    const float* bp      = (const float*)d_in[7];
    const float* Wbl     = (const float*)d_in[8];
    const float* Wac     = (const float*)d_in[9];
    const float* bac     = (const float*)d_in[10];
    const float* Wap     = (const float*)d_in[11];
    const float* bap     = (const float*)d_in[12];
    const float* Wcomb_c = (const float*)d_in[13];
    const float* bcomb_c = (const float*)d_in[14];
    const float* Wcomb_p = (const float*)d_in[15];
    const float* bcomb_p = (const float*)d_in[16];

    // ---- workspace: bf16 region, then fp32 region, then prepped weights ----
    u16t* prot_feat_bf = (u16t*)d_ws;                                    // B*LP*H
    u16t* comp_feat_bf = prot_feat_bf + (size_t)B_ * LP_ * H_;           // B*LC*H
    u16t* prot_proj_bf = comp_feat_bf + (size_t)B_ * LC_ * H_;           // 3*B*LP*H
    u16t* comp_proj_bf = prot_proj_bf + (size_t)3 * B_ * LP_ * H_;       // 3*B*LC*H
    u16t* comp_bil_bf  = comp_proj_bf + (size_t)3 * B_ * LC_ * H_;       // 3*B*LC*H
    float* f = (float*)(comp_bil_bf + (size_t)3 * B_ * LC_ * H_);
    float* Mbuf = f; f += (size_t)3 * B_ * HH_;
    float* Nbuf = f; f += (size_t)3 * B_ * HH_;
    float* vc = f;   f += (size_t)3 * B_ * H_;
    float* vp = f;   f += (size_t)3 * B_ * H_;
    float* logc = f; f += (size_t)3 * B_ * LC_;
    float* logp = f; f += (size_t)3 * B_ * LP_;
    float* cw = f;   f += (size_t)3 * B_ * LC_;
    float* pw = f;   f += (size_t)3 * B_ * LP_;
    float* cp = f;   f += 3 * B_ * H_;
    float* pp = f;   f += 3 * B_ * H_;
    float* part = f; f += (size_t)3 * 8 * B_ * HH_;  // 25.2 MB
    u16t* WHi  = (u16t*)f;                       // 9*HH (grp0=Wp,1=Wc,2=Wbl)
    u16t* WLo  = WHi + (size_t)9 * HH_;
    u16t* MNhi = WLo + (size_t)9 * HH_;          // 32*HH (0..15 = M lay2, 16..31 = N lay2)
    u16t* MNlo = MNhi + (size_t)32 * HH_;

    float* out_cf = (float*)d_out;
    float* out_pf = out_cf + B_ * H_;
    float* out_cc = out_pf + B_ * H_;
    float* out_pc = out_cc + (size_t)B_ * LC_ * H_;

    const int SL = 8;

    tobf16_k<<<dim3(B_ * LP_ * H_ / 8 / 256), 256, 0, stream>>>(
        (const float4*)prot_feat, (uint4*)prot_feat_bf);
    tobf16_k<<<dim3(B_ * LC_ * H_ / 8 / 256), 256, 0, stream>>>(
        (const float4*)comp_feat, (uint4*)comp_feat_bf);
    wprep3_k<<<dim3(3, 3), 256, 0, stream>>>(Wp, Wc, Wbl, WHi, WLo);
    hipMemsetAsync(cp, 0, (size_t)2 * 3 * B_ * H_ * sizeof(float), stream);
    hipMemsetAsync(d_out, 0, (size_t)2 * B_ * H_ * sizeof(float), stream);

    // projections (all 3 layers batched in grid z), W-fragments from global
    hgemm2_k<true, true, false, true><<<dim3(B_ * LP_ / 64, 2, 3), 256, 0, stream>>>(
        prot_feat_bf, WHi, WLo, bp, nullptr, prot_proj_bf, B_ * LP_);
    hgemm2_k<true, true, false, true><<<dim3(B_ * LC_ / 64, 2, 3), 256, 0, stream>>>(
        comp_feat_bf, WHi + (size_t)3 * HH_, WLo + (size_t)3 * HH_, bc, nullptr,
        comp_proj_bf, B_ * LC_);
    hgemm2_k<false, true, true, false><<<dim3(B_ * LC_ / 64, 2, 3), 256, 0, stream>>>(
        comp_proj_bf, WHi + (size_t)6 * HH_, WLo + (size_t)6 * HH_, nullptr, nullptr,
        comp_bil_bf, B_ * LC_);

    // M[lay] = P^T diag(pm) P ; N[lay] = Bil^T diag(cm) Cproj
    syrk_mfma_k<true><<<dim3(SL, B_, 3), 256, 128 * 68 * sizeof(short), stream>>>(
        prot_proj_bf, prot_proj_bf, prot_mask, part, LP_, LP_ / SL, SL);
    reduce_k<<<dim3(B_ * HH_ / 4 / 256, 3), 256, 0, stream>>>(
        (const float4*)part, (float4*)Mbuf, SL);
    syrk_mfma_k<false><<<dim3(SL, B_, 3), 256, 2 * 128 * 68 * sizeof(short), stream>>>(
        comp_bil_bf, comp_proj_bf, comp_mask, part, LC_, LC_ / SL, SL);
    reduce_k<<<dim3(B_ * HH_ / 4 / 256, 3), 256, 0, stream>>>(
        (const float4*)part, (float4*)Nbuf, SL);

    // v, logits, masked softmax
    mv_k<<<dim3(B_, 3), 256, 0, stream>>>(Mbuf, Nbuf, Wac, Wap, vc, vp);
    logits2_k<LC_><<<dim3(LC_ / 256, B_, 3), 256, 0, stream>>>(
        comp_bil_bf, comp_mask, vc, bac, logc);
    logits2_k<LP_><<<dim3(LP_ / 256, B_, 3), 256, 0, stream>>>(
        prot_proj_bf, prot_mask, vp, bap, logp);
    softmax_k<LC_><<<dim3(B_, 3), 256, 0, stream>>>(logc, comp_mask, cw);
    softmax_k<LP_><<<dim3(B_, 3), 256, 0, stream>>>(logp, prot_mask, pw);

    pool_k<<<dim3(B_, 4, 3), 256, 0, stream>>>(comp_proj_bf, cw, cp, LC_, 128);
    pool_k<<<dim3(B_, 16, 3), 256, 0, stream>>>(prot_proj_bf, pw, pp, LP_, 256);

    // layer-2 contexts: prep M/N hi-lo, then GEMM with per-b weight select
    wprepMN_k<<<dim3(B_, 2), 256, 0, stream>>>(Mbuf, Nbuf, MNhi, MNlo);
    hgemm2_k<false, false, true, false><<<dim3(LC_ / 64, 2, B_), 256, 0, stream>>>(
        comp_bil_bf + (size_t)2 * B_ * LC_ * H_, MNhi, MNlo,
        nullptr, comp_mask, out_cc, LC_);
    hgemm2_k<false, false, true, false><<<dim3(LP_ / 64, 2, B_), 256, 0, stream>>>(
        prot_proj_bf + (size_t)2 * B_ * LP_ * H_, MNhi + (size_t)B_ * HH_,
        MNlo + (size_t)B_ * HH_, nullptr, prot_mask, out_pc, LP_);

    final2_k<<<dim3(B_, 6), 128, 0, stream>>>(cp, Wcomb_c, bcomb_c, out_cf);
    final2_k<<<dim3(B_, 6), 128, 0, stream>>>(pp, Wcomb_p, bcomb_p, out_pf);
}